// Round 12
// baseline (228.536 us; speedup 1.0000x reference)
//
#include <hip/hip_runtime.h>
#include <math.h>

// LatentCompressedAttention on MI355X (gfx950), bf16-MFMA pipeline.
// B=2, S=2048, D=2048, H=16, Dh=128, LATENT=512, ROPE=64.

typedef __attribute__((ext_vector_type(8))) short bf16x8;    // 8 bf16 in 4 VGPRs
typedef __attribute__((ext_vector_type(4))) float f32x4;
typedef __attribute__((ext_vector_type(16))) float f32x16;

#define GLDS(gp, lp)                                                         \
  __builtin_amdgcn_global_load_lds(                                          \
      (const __attribute__((address_space(1))) void*)(gp),                   \
      (__attribute__((address_space(3))) void*)(lp), 16, 0, 0)

__device__ __forceinline__ short f2bf(float f) {
  unsigned u = __builtin_bit_cast(unsigned, f);
  u += 0x7fffu + ((u >> 16) & 1u);          // RNE
  return (short)(u >> 16);
}
__device__ __forceinline__ float b2f(short x) {
  unsigned u = ((unsigned)(unsigned short)x) << 16;
  return __builtin_bit_cast(float, u);
}
// HW packed f32->bf16 (v_cvt_pk_bf16_f32; lo in low short)
__device__ __forceinline__ unsigned cvtpk(float lo, float hi) {
  unsigned r;
  asm("v_cvt_pk_bf16_f32 %0, %1, %2" : "=v"(r) : "v"(lo), "v"(hi));
  return r;
}

// ------------------------------------------------------------ fused prep ----
// One kernel for all preprocessing.  Block ranges:
//   [0,8192)        cast x -> bf16
//   [8192,16384)    transpose Wq (z=0) / Wo (z=1), K=2048 N=2048
//   [16384,17408)   transpose Wc, K=2048 N=512
//   [17408,19456)   transpose Wk (z=0) / Wv (z=1), K=512 N=2048
//   [19456,19712)   rope cos/sin table [2048][32]
__device__ __forceinline__ void transpose_body(const float* __restrict__ W,
                                               short* __restrict__ Wt,
                                               int K, int N, int n0, int k0,
                                               float (*tile)[33]) {
  int tx = threadIdx.x & 31, ty = threadIdx.x >> 5;   // ty in 0..7
#pragma unroll
  for (int i = 0; i < 4; ++i)
    tile[ty + i * 8][tx] = W[(size_t)(k0 + ty + i * 8) * N + n0 + tx];
  __syncthreads();
#pragma unroll
  for (int i = 0; i < 4; ++i)
    Wt[(size_t)(n0 + ty + i * 8) * K + k0 + tx] = f2bf(tile[tx][ty + i * 8]);
}

__global__ void prep_kernel(const float* __restrict__ x, short* __restrict__ xb,
                            const float* __restrict__ Wq, short* __restrict__ wqT,
                            const float* __restrict__ Wo, short* __restrict__ woT,
                            const float* __restrict__ Wc, short* __restrict__ wcT,
                            const float* __restrict__ Wk, short* __restrict__ wkT,
                            const float* __restrict__ Wv, short* __restrict__ wvT,
                            const int* __restrict__ pos, float* __restrict__ cosT,
                            float* __restrict__ sinT) {
  __shared__ float tile[32][33];
  const int bid = blockIdx.x;
  if (bid < 8192) {
    int i = bid * 256 + threadIdx.x;            // n4 = 2097152 exactly
    float4 v = ((const float4*)x)[i];
    ushort4 o;
    o.x = (unsigned short)f2bf(v.x);
    o.y = (unsigned short)f2bf(v.y);
    o.z = (unsigned short)f2bf(v.z);
    o.w = (unsigned short)f2bf(v.w);
    ((ushort4*)xb)[i] = o;
  } else if (bid < 16384) {
    int local = bid - 8192;
    int z = local >> 12, rem = local & 4095;
    transpose_body(z ? Wo : Wq, z ? woT : wqT, 2048, 2048,
                   (rem & 63) * 32, (rem >> 6) * 32, tile);
  } else if (bid < 17408) {
    int local = bid - 16384;
    transpose_body(Wc, wcT, 2048, 512, (local & 15) * 32, (local >> 4) * 32, tile);
  } else if (bid < 19456) {
    int local = bid - 17408;
    int z = local >> 10, rem = local & 1023;
    transpose_body(z ? Wv : Wk, z ? wvT : wkT, 512, 2048,
                   (rem & 63) * 32, (rem >> 6) * 32, tile);
  } else {
    int idx = (bid - 19456) * 256 + threadIdx.x;   // 65536 = 2048*32 exactly
    int s = idx >> 5, i = idx & 31;
    float p = (float)pos[s];
    // 10000^(-i/32) = exp2(-i * log2(10000)/32)
    float freq = p * exp2f(-(float)i * 0.41524101186092029f);
    float sv, cv;
    sincosf(freq, &sv, &cv);
    cosT[idx] = cv;
    sinT[idx] = sv;
  }
}

// ----------------------------------------------------------------- GEMM ----
// R7-verified core. C = A[M,K] @ Bt[N,K]^T, bf16, 128x128 tile, BK=64,
// 4 waves, T2 XOR-swizzle (rule 21: linear dest + inv-swz source + swz read).
template <int MODE>
__device__ __forceinline__ void gemm_core(const short* __restrict__ A,
                                          const short* __restrict__ Bt,
                                          void* __restrict__ Cv,
                                          int N, int K, int bm, int bn,
                                          short* sm) {
  const int tid  = threadIdx.x;
  const int lane = tid & 63;
  const int w    = tid >> 6;
  const int col  = lane & 15, g = lane >> 4;
  const int wr = w >> 1, wc = w & 1;

  f32x4 zero4 = {0.f, 0.f, 0.f, 0.f};
  f32x4 acc[4][4];
#pragma unroll
  for (int m = 0; m < 4; ++m)
#pragma unroll
    for (int n = 0; n < 4; ++n) acc[m][n] = zero4;

  const int sr = tid >> 3;            // 0..31: row within a 32-row round
  const int sk = tid & 7;             // 16B chunk within the 128B row

  auto STAGE = [&](int buf, int t) {
#pragma unroll
    for (int i = 0; i < 4; ++i) {
      int r = i * 32 + sr;
      int c = (sk ^ (r & 7)) << 3;    // inverse-swizzled global chunk
      GLDS(A  + (size_t)(bm + r) * K + t * 64 + c,
           sm + buf * 8192 + i * 2048 + w * 512);
      GLDS(Bt + (size_t)(bn + r) * K + t * 64 + c,
           sm + 16384 + buf * 8192 + i * 2048 + w * 512);
    }
  };

  const int nt = K >> 6;
  STAGE(0, 0);
  __syncthreads();
  int buf = 0;
  for (int t = 0; t < nt; ++t) {
    if (t + 1 < nt) STAGE(buf ^ 1, t + 1);     // async prefetch into other buffer
    const short* As = sm + buf * 8192;
    const short* Bs = sm + 16384 + buf * 8192;
#pragma unroll
    for (int kk = 0; kk < 2; ++kk) {
      bf16x8 la[4], lb[4];
#pragma unroll
      for (int m = 0; m < 4; ++m) {
        int row = wr * 64 + m * 16 + col;
        la[m] = *(const bf16x8*)(As + row * 64 + (((kk * 4 + g) ^ (row & 7)) << 3));
      }
#pragma unroll
      for (int n = 0; n < 4; ++n) {
        int row = wc * 64 + n * 16 + col;
        lb[n] = *(const bf16x8*)(Bs + row * 64 + (((kk * 4 + g) ^ (row & 7)) << 3));
      }
#pragma unroll
      for (int m = 0; m < 4; ++m)
#pragma unroll
        for (int n = 0; n < 4; ++n)
          acc[m][n] = __builtin_amdgcn_mfma_f32_16x16x32_bf16(la[m], lb[n], acc[m][n], 0, 0, 0);
    }
    __syncthreads();   // drains vmcnt(0)+lgkmcnt before barrier
    buf ^= 1;
  }

  const int orow0 = bm + wr * 64;
  const int ocol0 = bn + wc * 64;
  if (MODE == 0) {
    short* C = (short*)Cv;
#pragma unroll
    for (int m = 0; m < 4; ++m)
#pragma unroll
      for (int n = 0; n < 4; ++n)
#pragma unroll
        for (int r = 0; r < 4; ++r)
          C[(size_t)(orow0 + m * 16 + g * 4 + r) * N + ocol0 + n * 16 + col] =
              f2bf(acc[m][n][r]);
  } else if (MODE == 1) {
    float* C = (float*)Cv;
#pragma unroll
    for (int m = 0; m < 4; ++m)
#pragma unroll
      for (int n = 0; n < 4; ++n)
#pragma unroll
        for (int r = 0; r < 4; ++r)
          C[(size_t)(orow0 + m * 16 + g * 4 + r) * N + ocol0 + n * 16 + col] =
              acc[m][n][r];
  } else {
    // Vt[(b*2048 + n)*2048 + s]; 4 acc rows are 4 consecutive s -> one 8B store.
    short* C = (short*)Cv;
#pragma unroll
    for (int m = 0; m < 4; ++m)
#pragma unroll
      for (int n = 0; n < 4; ++n) {
        int grow = orow0 + m * 16 + g * 4;
        int bb = grow >> 11, s = grow & 2047;
        int cn = ocol0 + n * 16 + col;
        ushort4 pk;
        pk.x = (unsigned short)f2bf(acc[m][n][0]);
        pk.y = (unsigned short)f2bf(acc[m][n][1]);
        pk.z = (unsigned short)f2bf(acc[m][n][2]);
        pk.w = (unsigned short)f2bf(acc[m][n][3]);
        *(ushort4*)(C + ((size_t)(bb * 2048 + cn)) * 2048 + s) = pk;
      }
  }
}

// 1D-grid wrappers with T1 bijective XCD chunk remap (nwg%8==0 for all):
// each XCD gets consecutive y-rows -> A-panels become L2-resident.
__global__ __launch_bounds__(256, 2) void gemm_qc(const short* __restrict__ xb,
                                                  const short* __restrict__ wqT,
                                                  const short* __restrict__ wcT,
                                                  short* __restrict__ qb,
                                                  short* __restrict__ kvb) {
  __shared__ alignas(16) short sm[32768];
  int lin = blockIdx.x;                       // 640 blocks
  int swz = (lin & 7) * 80 + (lin >> 3);      // XCD gets y in [xcd*4, xcd*4+4)
  int x = swz % 20, y = swz / 20;
  if (x < 16) gemm_core<0>(xb, wqT, qb, 2048, 2048, y * 128, x * 128, sm);
  else        gemm_core<0>(xb, wcT, kvb, 512, 2048, y * 128, (x - 16) * 128, sm);
}
__global__ __launch_bounds__(256, 2) void gemm_kv(const short* __restrict__ kvb,
                                                  const short* __restrict__ wkT,
                                                  const short* __restrict__ wvT,
                                                  short* __restrict__ kb,
                                                  short* __restrict__ vtb) {
  __shared__ alignas(16) short sm[32768];
  int lin = blockIdx.x;                       // 1024 blocks
  int swz = (lin & 7) * 128 + (lin >> 3);     // XCD gets y in [xcd*4, xcd*4+4)
  int x = swz & 31, y = swz >> 5;
  if (x < 16) gemm_core<0>(kvb, wkT, kb, 2048, 512, y * 128, x * 128, sm);
  else        gemm_core<2>(kvb, wvT, vtb, 2048, 512, y * 128, (x - 16) * 128, sm);
}
__global__ __launch_bounds__(256, 2) void gemm_wo(const short* __restrict__ obuf,
                                                  const short* __restrict__ woT,
                                                  float* __restrict__ out) {
  __shared__ alignas(16) short sm[32768];
  int lin = blockIdx.x;                       // 512 blocks
  int swz = (lin & 7) * 64 + (lin >> 3);      // XCD gets y in [xcd*2, xcd*2+2)
  int x = swz & 15, y = swz >> 4;
  gemm_core<1>(obuf, woT, out, 2048, 2048, y * 128, x * 128, sm);
}

// ------------------------------------------------------------ attention ----
// R10-verified structure.  Swapped-operand 32x32: S^T = K @ Q^T ;
// O^T = V^T @ P^T ; lane owns one q-row's softmax state.  XCD-locality grid,
// log2-domain softmax, defer-max THR=8, cvt_pk packing, split QK chains.
// NEW vs R11: cl2 folded into Q fragments (one-time; deletes per-tile scale
// pass); PV accumulator split into o/o2 (halves PV dep-chain, same mechanism
// as the verified QK split).  pf slot assignment FROZEN from R4.
__global__ __launch_bounds__(256, 2) void attn_kernel(
    const short* __restrict__ qb, const short* __restrict__ kb,
    const short* __restrict__ vt, short* __restrict__ ob,
    const float* __restrict__ cosT, const float* __restrict__ sinT) {
  // shorts: K bufs @0,8192 ([64 keys][128 d]); V bufs @16384,24576 ([128 d][64 keys])
  __shared__ alignas(16) short sm[32768];
  const int lane = threadIdx.x & 63, w = threadIdx.x >> 6;
  const int ql = lane & 31, hi = lane >> 5;
  const int qt = blockIdx.x >> 5, bh = blockIdx.x & 31;   // bid = qt*32+bh -> XCD=bh%8
  const int b = bh >> 4, h = bh & 15;
  const int q0w = qt * 128 + w * 32;
  const int qrow = q0w + ql;

  const float cl2 = 0.12752744590518352f;   // (1/sqrt(128)) * log2(e)

  // ---- Q load (B-fragment layout: lane q=ql, d = db*16 + hi*8 + j) + RoPE,
  // ---- with cl2 folded into every q dim (one-time; exonerated by R2/R3 bisect)
  bf16x8 qf[8];
  {
    const short* qp = qb + ((size_t)(b * 2048 + qrow)) * 2048 + h * 128;
#pragma unroll
    for (int db = 0; db < 8; ++db) qf[db] = *(const bf16x8*)(qp + db * 16 + hi * 8);
    const float* cp = cosT + qrow * 32;
    const float* sp = sinT + qrow * 32;
#pragma unroll
    for (int db = 0; db < 2; ++db)
#pragma unroll
      for (int j = 0; j < 8; ++j) {
        int i = db * 16 + hi * 8 + j;
        float x1 = b2f(qf[db][j]), x2 = b2f(qf[db + 2][j]);
        float cv = cp[i], sv = sp[i];
        qf[db][j]     = f2bf((x1 * cv - x2 * sv) * cl2);
        qf[db + 2][j] = f2bf((x1 * sv + x2 * cv) * cl2);
      }
#pragma unroll
    for (int db = 4; db < 8; ++db)
#pragma unroll
      for (int j = 0; j < 8; ++j) qf[db][j] = f2bf(b2f(qf[db][j]) * cl2);
  }

  f32x16 o[4], o2[4];
#pragma unroll
  for (int m4 = 0; m4 < 4; ++m4)
#pragma unroll
    for (int r = 0; r < 16; ++r) { o[m4][r] = 0.f; o2[m4][r] = 0.f; }
  float mrun = -3.0e38f, lrun = 0.f;

  auto STAGE = [&](int buf, int kt) {
    // K tile [64 keys][128 d]: linear LDS dest, inverse-swizzled global src.
#pragma unroll
    for (int i = 0; i < 4; ++i) {
      int r = w * 16 + i * 4 + (lane >> 4);
      int cch = lane & 15;
      const short* gp = kb + ((size_t)(b * 2048 + kt * 64 + r)) * 2048 + h * 128 +
                        ((cch ^ (r & 7)) << 3);
      GLDS(gp, sm + buf * 8192 + w * 2048 + i * 512);
    }
    // V^T tile [128 d][64 keys]
#pragma unroll
    for (int i = 0; i < 4; ++i) {
      int rd = w * 32 + i * 8 + (lane >> 3);
      int cch = lane & 7;
      const short* gp = vt + ((size_t)(b * 2048 + h * 128 + rd)) * 2048 + kt * 64 +
                        ((cch ^ (rd & 7)) << 3);
      GLDS(gp, sm + 16384 + buf * 8192 + w * 2048 + i * 512);
    }
  };

  STAGE(0, 0);
  __syncthreads();
  int buf = 0;
  for (int kt = 0; kt < 32; ++kt) {
    if (kt + 1 < 32) STAGE(buf ^ 1, kt + 1);
    const short* Ks = sm + buf * 8192;
    const short* Vs = sm + 16384 + buf * 8192;

    // ---- QK^T (swapped): skt[kb2] = S^T[key block kb2][q]; two independent
    // 4-long MFMA chains per kb2 (scale pre-folded into Q).
    f32x16 skt[2];
    __builtin_amdgcn_s_setprio(1);
#pragma unroll
    for (int kb2 = 0; kb2 < 2; ++kb2) {
      f32x16 a0, a1;
#pragma unroll
      for (int r = 0; r < 16; ++r) { a0[r] = 0.f; a1[r] = 0.f; }
      int krow = kb2 * 32 + ql;
#pragma unroll
      for (int db = 0; db < 4; ++db) {
        bf16x8 kf = *(const bf16x8*)(Ks + krow * 128 + (((db * 2 + hi) ^ (krow & 7)) << 3));
        a0 = __builtin_amdgcn_mfma_f32_32x32x16_bf16(kf, qf[db], a0, 0, 0, 0);
      }
#pragma unroll
      for (int db = 4; db < 8; ++db) {
        bf16x8 kf = *(const bf16x8*)(Ks + krow * 128 + (((db * 2 + hi) ^ (krow & 7)) << 3));
        a1 = __builtin_amdgcn_mfma_f32_32x32x16_bf16(kf, qf[db], a1, 0, 0, 0);
      }
#pragma unroll
      for (int r = 0; r < 16; ++r) skt[kb2][r] = a0[r] + a1[r];
    }
    __builtin_amdgcn_s_setprio(0);

    // ---- row-max via max tree (4 chains of 8, then combine, then half-swap)
    float t0, t1, t2, t3;
    t0 = fmaxf(fmaxf(fmaxf(fmaxf(skt[0][0], skt[0][4]), skt[0][8]),
                     fmaxf(skt[0][12], skt[1][0])),
               fmaxf(fmaxf(skt[1][4], skt[1][8]), skt[1][12]));
    t1 = fmaxf(fmaxf(fmaxf(fmaxf(skt[0][1], skt[0][5]), skt[0][9]),
                     fmaxf(skt[0][13], skt[1][1])),
               fmaxf(fmaxf(skt[1][5], skt[1][9]), skt[1][13]));
    t2 = fmaxf(fmaxf(fmaxf(fmaxf(skt[0][2], skt[0][6]), skt[0][10]),
                     fmaxf(skt[0][14], skt[1][2])),
               fmaxf(fmaxf(skt[1][6], skt[1][10]), skt[1][14]));
    t3 = fmaxf(fmaxf(fmaxf(fmaxf(skt[0][3], skt[0][7]), skt[0][11]),
                     fmaxf(skt[0][15], skt[1][3])),
               fmaxf(fmaxf(skt[1][7], skt[1][11]), skt[1][15]));
    float tmax = fmaxf(fmaxf(t0, t1), fmaxf(t2, t3));
    tmax = fmaxf(tmax, __shfl_xor(tmax, 32));

    // ---- defer-max (T13): rescale only when max grew by > 8 (log2 domain)
    if (!__all(tmax <= mrun + 8.0f)) {
      float mn = fmaxf(mrun, tmax);
      float fr = __builtin_amdgcn_exp2f(mrun - mn);
      mrun = mn;
      lrun *= fr;
#pragma unroll
      for (int m4 = 0; m4 < 4; ++m4)
#pragma unroll
        for (int r = 0; r < 16; ++r) { o[m4][r] *= fr; o2[m4][r] *= fr; }
    }
    // ---- exp2 in place + row-sum
    float s0 = 0.f, s1 = 0.f, s2 = 0.f, s3 = 0.f;
#pragma unroll
    for (int kb2 = 0; kb2 < 2; ++kb2)
#pragma unroll
      for (int r = 0; r < 16; r += 4) {
        skt[kb2][r]     = __builtin_amdgcn_exp2f(skt[kb2][r] - mrun);
        skt[kb2][r + 1] = __builtin_amdgcn_exp2f(skt[kb2][r + 1] - mrun);
        skt[kb2][r + 2] = __builtin_amdgcn_exp2f(skt[kb2][r + 2] - mrun);
        skt[kb2][r + 3] = __builtin_amdgcn_exp2f(skt[kb2][r + 3] - mrun);
        s0 += skt[kb2][r];     s1 += skt[kb2][r + 1];
        s2 += skt[kb2][r + 2]; s3 += skt[kb2][r + 3];
      }
    float psum = (s0 + s1) + (s2 + s3);
    psum += __shfl_xor(psum, 32);
    lrun += psum;

    // ---- P -> bf16 P^T B-fragments (slot assignment FROZEN from R4).
    bf16x8 pf[4];
#pragma unroll
    for (int kb2 = 0; kb2 < 2; ++kb2) {
#pragma unroll
      for (int half = 0; half < 2; ++half) {
        unsigned a0 = cvtpk(skt[kb2][half * 8 + 0], skt[kb2][half * 8 + 1]);
        unsigned a1 = cvtpk(skt[kb2][half * 8 + 2], skt[kb2][half * 8 + 3]);
        unsigned b0 = cvtpk(skt[kb2][half * 8 + 4], skt[kb2][half * 8 + 5]);
        unsigned b1 = cvtpk(skt[kb2][half * 8 + 6], skt[kb2][half * 8 + 7]);
        unsigned pa0 = __shfl_xor(a0, 32), pa1 = __shfl_xor(a1, 32);
        unsigned pb0 = __shfl_xor(b0, 32), pb1 = __shfl_xor(b1, 32);
        union { unsigned u[4]; bf16x8 v; } tmp;
        tmp.u[0] = hi ? pb0 : a0;
        tmp.u[1] = hi ? pb1 : a1;
        tmp.u[2] = hi ? b0 : pa0;
        tmp.u[3] = hi ? b1 : pa1;
        pf[kb2 * 2 + half] = tmp.v;
      }
    }

    // ---- PV (swapped): O^T[d][q] += V^T @ P^T; split accumulators
    // (ks 0,1 -> o; ks 2,3 -> o2) halve the per-m4 dependency chain.
    __builtin_amdgcn_s_setprio(1);
#pragma unroll
    for (int m4 = 0; m4 < 4; ++m4) {
      int rd = m4 * 32 + ql;
#pragma unroll
      for (int ks = 0; ks < 2; ++ks) {
        bf16x8 vf = *(const bf16x8*)(Vs + rd * 64 + (((ks * 2 + hi) ^ (rd & 7)) << 3));
        o[m4] = __builtin_amdgcn_mfma_f32_32x32x16_bf16(vf, pf[ks], o[m4], 0, 0, 0);
      }
#pragma unroll
      for (int ks = 2; ks < 4; ++ks) {
        bf16x8 vf = *(const bf16x8*)(Vs + rd * 64 + (((ks * 2 + hi) ^ (rd & 7)) << 3));
        o2[m4] = __builtin_amdgcn_mfma_f32_32x32x16_bf16(vf, pf[ks], o2[m4], 0, 0, 0);
      }
    }
    __builtin_amdgcn_s_setprio(0);
    __syncthreads();
    buf ^= 1;
  }

  // ---- epilogue: combine o+o2, O^T -> LDS transpose -> coalesced bf16 store
  float il = 1.0f / lrun;
  short* E = sm + w * 4352;                    // [32 q][136 shorts], 16B-aligned rows
#pragma unroll
  for (int m4 = 0; m4 < 4; ++m4)
#pragma unroll
    for (int r = 0; r < 16; r += 2) {
      int d = m4 * 32 + (r & 3) + 8 * (r >> 2) + 4 * hi;
      unsigned pk = cvtpk((o[m4][r] + o2[m4][r]) * il,
                          (o[m4][r + 1] + o2[m4][r + 1]) * il);
      *(unsigned*)(E + ql * 136 + d) = pk;
    }
  asm volatile("s_waitcnt lgkmcnt(0)" ::: "memory");   // wave-private region
#pragma unroll
  for (int it = 0; it < 8; ++it) {
    int row = it * 4 + (lane >> 4);
    int ch = lane & 15;
    bf16x8 v = *(const bf16x8*)(E + row * 136 + ch * 8);
    *(bf16x8*)(ob + ((size_t)(b * 2048 + q0w + row)) * 2048 + h * 128 + ch * 8) = v;
  }
}

// --------------------------------------------------------------- launch ----
extern "C" void kernel_launch(void* const* d_in, const int* in_sizes, int n_in,
                              void* d_out, int out_size, void* d_ws, size_t ws_size,
                              hipStream_t stream) {
  (void)in_sizes; (void)n_in; (void)out_size; (void)ws_size;
  const float* x  = (const float*)d_in[0];
  const int*   pos = (const int*)d_in[1];
  const float* Wq = (const float*)d_in[2];
  const float* Wc = (const float*)d_in[3];
  const float* Wk = (const float*)d_in[4];
  const float* Wv = (const float*)d_in[5];
  const float* Wo = (const float*)d_in[6];

  char* ws = (char*)d_ws;
  short* xb   = (short*)(ws);                 // x bf16            16.78 MB
  short* qb   = (short*)(ws + 16777216);      // q (pre-rope)      16.78 MB
  short* kvb  = (short*)(ws + 33554432);      // latent            4.19 MB
  short* kb   = (short*)(ws + 37748736);      // k                 16.78 MB
  short* vtb  = (short*)(ws + 54525952);      // v transposed      16.78 MB
  short* obuf = (short*)(ws + 71303168);      // attn out          16.78 MB
  short* wqT  = (short*)(ws + 88080384);      // Wq^T              8.39 MB
  short* wcT  = (short*)(ws + 96468992);      // Wc^T              2.10 MB
  short* wkT  = (short*)(ws + 98566144);      // Wk^T              2.10 MB
  short* wvT  = (short*)(ws + 100663296);     // Wv^T              2.10 MB
  short* woT  = (short*)(ws + 102760448);     // Wo^T              8.39 MB
  float* cosT = (float*)(ws + 111149056);     // 0.26 MB
  float* sinT = (float*)(ws + 111411200);     // 0.26 MB

  prep_kernel<<<19712, 256, 0, stream>>>(x, xb, Wq, wqT, Wo, woT, Wc, wcT,
                                         Wk, wkT, Wv, wvT, pos, cosT, sinT);

  gemm_qc<<<640, 256, 0, stream>>>(xb, wqT, wcT, qb, kvb);
  gemm_kv<<<1024, 256, 0, stream>>>(kvb, wkT, wvT, kb, vtb);

  attn_kernel<<<512, 256, 0, stream>>>(qb, kb, vtb, obuf, cosT, sinT);

  gemm_wo<<<512, 256, 0, stream>>>(obuf, woT, (float*)d_out);
}

// Round 13
// 222.783 us; speedup vs baseline: 1.0258x; 1.0258x over previous
//
#include <hip/hip_runtime.h>
#include <math.h>

// LatentCompressedAttention on MI355X (gfx950), bf16-MFMA pipeline.
// B=2, S=2048, D=2048, H=16, Dh=128, LATENT=512, ROPE=64.
// R13 = best-known config: R10/R11-verified attn (97.5us) + T1 GEMM wrappers
// + fused prep.  R12's cl2-fold + PV-split reverted (VGPR 108->128 cost more
// than the dep-chain split saved).

typedef __attribute__((ext_vector_type(8))) short bf16x8;    // 8 bf16 in 4 VGPRs
typedef __attribute__((ext_vector_type(4))) float f32x4;
typedef __attribute__((ext_vector_type(16))) float f32x16;

#define GLDS(gp, lp)                                                         \
  __builtin_amdgcn_global_load_lds(                                          \
      (const __attribute__((address_space(1))) void*)(gp),                   \
      (__attribute__((address_space(3))) void*)(lp), 16, 0, 0)

__device__ __forceinline__ short f2bf(float f) {
  unsigned u = __builtin_bit_cast(unsigned, f);
  u += 0x7fffu + ((u >> 16) & 1u);          // RNE
  return (short)(u >> 16);
}
__device__ __forceinline__ float b2f(short x) {
  unsigned u = ((unsigned)(unsigned short)x) << 16;
  return __builtin_bit_cast(float, u);
}
// HW packed f32->bf16 (v_cvt_pk_bf16_f32; lo in low short)
__device__ __forceinline__ unsigned cvtpk(float lo, float hi) {
  unsigned r;
  asm("v_cvt_pk_bf16_f32 %0, %1, %2" : "=v"(r) : "v"(lo), "v"(hi));
  return r;
}

// ------------------------------------------------------------ fused prep ----
// One kernel for all preprocessing.  Block ranges:
//   [0,8192)        cast x -> bf16
//   [8192,16384)    transpose Wq (z=0) / Wo (z=1), K=2048 N=2048
//   [16384,17408)   transpose Wc, K=2048 N=512
//   [17408,19456)   transpose Wk (z=0) / Wv (z=1), K=512 N=2048
//   [19456,19712)   rope cos/sin table [2048][32]
__device__ __forceinline__ void transpose_body(const float* __restrict__ W,
                                               short* __restrict__ Wt,
                                               int K, int N, int n0, int k0,
                                               float (*tile)[33]) {
  int tx = threadIdx.x & 31, ty = threadIdx.x >> 5;   // ty in 0..7
#pragma unroll
  for (int i = 0; i < 4; ++i)
    tile[ty + i * 8][tx] = W[(size_t)(k0 + ty + i * 8) * N + n0 + tx];
  __syncthreads();
#pragma unroll
  for (int i = 0; i < 4; ++i)
    Wt[(size_t)(n0 + ty + i * 8) * K + k0 + tx] = f2bf(tile[tx][ty + i * 8]);
}

__global__ void prep_kernel(const float* __restrict__ x, short* __restrict__ xb,
                            const float* __restrict__ Wq, short* __restrict__ wqT,
                            const float* __restrict__ Wo, short* __restrict__ woT,
                            const float* __restrict__ Wc, short* __restrict__ wcT,
                            const float* __restrict__ Wk, short* __restrict__ wkT,
                            const float* __restrict__ Wv, short* __restrict__ wvT,
                            const int* __restrict__ pos, float* __restrict__ cosT,
                            float* __restrict__ sinT) {
  __shared__ float tile[32][33];
  const int bid = blockIdx.x;
  if (bid < 8192) {
    int i = bid * 256 + threadIdx.x;            // n4 = 2097152 exactly
    float4 v = ((const float4*)x)[i];
    ushort4 o;
    o.x = (unsigned short)f2bf(v.x);
    o.y = (unsigned short)f2bf(v.y);
    o.z = (unsigned short)f2bf(v.z);
    o.w = (unsigned short)f2bf(v.w);
    ((ushort4*)xb)[i] = o;
  } else if (bid < 16384) {
    int local = bid - 8192;
    int z = local >> 12, rem = local & 4095;
    transpose_body(z ? Wo : Wq, z ? woT : wqT, 2048, 2048,
                   (rem & 63) * 32, (rem >> 6) * 32, tile);
  } else if (bid < 17408) {
    int local = bid - 16384;
    transpose_body(Wc, wcT, 2048, 512, (local & 15) * 32, (local >> 4) * 32, tile);
  } else if (bid < 19456) {
    int local = bid - 17408;
    int z = local >> 10, rem = local & 1023;
    transpose_body(z ? Wv : Wk, z ? wvT : wkT, 512, 2048,
                   (rem & 63) * 32, (rem >> 6) * 32, tile);
  } else {
    int idx = (bid - 19456) * 256 + threadIdx.x;   // 65536 = 2048*32 exactly
    int s = idx >> 5, i = idx & 31;
    float p = (float)pos[s];
    // 10000^(-i/32) = exp2(-i * log2(10000)/32)
    float freq = p * exp2f(-(float)i * 0.41524101186092029f);
    float sv, cv;
    sincosf(freq, &sv, &cv);
    cosT[idx] = cv;
    sinT[idx] = sv;
  }
}

// ----------------------------------------------------------------- GEMM ----
// R7-verified core. C = A[M,K] @ Bt[N,K]^T, bf16, 128x128 tile, BK=64,
// 4 waves, T2 XOR-swizzle (rule 21: linear dest + inv-swz source + swz read).
template <int MODE>
__device__ __forceinline__ void gemm_core(const short* __restrict__ A,
                                          const short* __restrict__ Bt,
                                          void* __restrict__ Cv,
                                          int N, int K, int bm, int bn,
                                          short* sm) {
  const int tid  = threadIdx.x;
  const int lane = tid & 63;
  const int w    = tid >> 6;
  const int col  = lane & 15, g = lane >> 4;
  const int wr = w >> 1, wc = w & 1;

  f32x4 zero4 = {0.f, 0.f, 0.f, 0.f};
  f32x4 acc[4][4];
#pragma unroll
  for (int m = 0; m < 4; ++m)
#pragma unroll
    for (int n = 0; n < 4; ++n) acc[m][n] = zero4;

  const int sr = tid >> 3;            // 0..31: row within a 32-row round
  const int sk = tid & 7;             // 16B chunk within the 128B row

  auto STAGE = [&](int buf, int t) {
#pragma unroll
    for (int i = 0; i < 4; ++i) {
      int r = i * 32 + sr;
      int c = (sk ^ (r & 7)) << 3;    // inverse-swizzled global chunk
      GLDS(A  + (size_t)(bm + r) * K + t * 64 + c,
           sm + buf * 8192 + i * 2048 + w * 512);
      GLDS(Bt + (size_t)(bn + r) * K + t * 64 + c,
           sm + 16384 + buf * 8192 + i * 2048 + w * 512);
    }
  };

  const int nt = K >> 6;
  STAGE(0, 0);
  __syncthreads();
  int buf = 0;
  for (int t = 0; t < nt; ++t) {
    if (t + 1 < nt) STAGE(buf ^ 1, t + 1);     // async prefetch into other buffer
    const short* As = sm + buf * 8192;
    const short* Bs = sm + 16384 + buf * 8192;
#pragma unroll
    for (int kk = 0; kk < 2; ++kk) {
      bf16x8 la[4], lb[4];
#pragma unroll
      for (int m = 0; m < 4; ++m) {
        int row = wr * 64 + m * 16 + col;
        la[m] = *(const bf16x8*)(As + row * 64 + (((kk * 4 + g) ^ (row & 7)) << 3));
      }
#pragma unroll
      for (int n = 0; n < 4; ++n) {
        int row = wc * 64 + n * 16 + col;
        lb[n] = *(const bf16x8*)(Bs + row * 64 + (((kk * 4 + g) ^ (row & 7)) << 3));
      }
#pragma unroll
      for (int m = 0; m < 4; ++m)
#pragma unroll
        for (int n = 0; n < 4; ++n)
          acc[m][n] = __builtin_amdgcn_mfma_f32_16x16x32_bf16(la[m], lb[n], acc[m][n], 0, 0, 0);
    }
    __syncthreads();   // drains vmcnt(0)+lgkmcnt before barrier
    buf ^= 1;
  }

  const int orow0 = bm + wr * 64;
  const int ocol0 = bn + wc * 64;
  if (MODE == 0) {
    short* C = (short*)Cv;
#pragma unroll
    for (int m = 0; m < 4; ++m)
#pragma unroll
      for (int n = 0; n < 4; ++n)
#pragma unroll
        for (int r = 0; r < 4; ++r)
          C[(size_t)(orow0 + m * 16 + g * 4 + r) * N + ocol0 + n * 16 + col] =
              f2bf(acc[m][n][r]);
  } else if (MODE == 1) {
    float* C = (float*)Cv;
#pragma unroll
    for (int m = 0; m < 4; ++m)
#pragma unroll
      for (int n = 0; n < 4; ++n)
#pragma unroll
        for (int r = 0; r < 4; ++r)
          C[(size_t)(orow0 + m * 16 + g * 4 + r) * N + ocol0 + n * 16 + col] =
              acc[m][n][r];
  } else {
    // Vt[(b*2048 + n)*2048 + s]; 4 acc rows are 4 consecutive s -> one 8B store.
    short* C = (short*)Cv;
#pragma unroll
    for (int m = 0; m < 4; ++m)
#pragma unroll
      for (int n = 0; n < 4; ++n) {
        int grow = orow0 + m * 16 + g * 4;
        int bb = grow >> 11, s = grow & 2047;
        int cn = ocol0 + n * 16 + col;
        ushort4 pk;
        pk.x = (unsigned short)f2bf(acc[m][n][0]);
        pk.y = (unsigned short)f2bf(acc[m][n][1]);
        pk.z = (unsigned short)f2bf(acc[m][n][2]);
        pk.w = (unsigned short)f2bf(acc[m][n][3]);
        *(ushort4*)(C + ((size_t)(bb * 2048 + cn)) * 2048 + s) = pk;
      }
  }
}

// 1D-grid wrappers with T1 bijective XCD chunk remap (neutral-to-positive
// in R12 A/B; kept).
__global__ __launch_bounds__(256, 2) void gemm_qc(const short* __restrict__ xb,
                                                  const short* __restrict__ wqT,
                                                  const short* __restrict__ wcT,
                                                  short* __restrict__ qb,
                                                  short* __restrict__ kvb) {
  __shared__ alignas(16) short sm[32768];
  int lin = blockIdx.x;                       // 640 blocks
  int swz = (lin & 7) * 80 + (lin >> 3);      // XCD gets y in [xcd*4, xcd*4+4)
  int x = swz % 20, y = swz / 20;
  if (x < 16) gemm_core<0>(xb, wqT, qb, 2048, 2048, y * 128, x * 128, sm);
  else        gemm_core<0>(xb, wcT, kvb, 512, 2048, y * 128, (x - 16) * 128, sm);
}
__global__ __launch_bounds__(256, 2) void gemm_kv(const short* __restrict__ kvb,
                                                  const short* __restrict__ wkT,
                                                  const short* __restrict__ wvT,
                                                  short* __restrict__ kb,
                                                  short* __restrict__ vtb) {
  __shared__ alignas(16) short sm[32768];
  int lin = blockIdx.x;                       // 1024 blocks
  int swz = (lin & 7) * 128 + (lin >> 3);     // XCD gets y in [xcd*4, xcd*4+4)
  int x = swz & 31, y = swz >> 5;
  if (x < 16) gemm_core<0>(kvb, wkT, kb, 2048, 512, y * 128, x * 128, sm);
  else        gemm_core<2>(kvb, wvT, vtb, 2048, 512, y * 128, (x - 16) * 128, sm);
}
__global__ __launch_bounds__(256, 2) void gemm_wo(const short* __restrict__ obuf,
                                                  const short* __restrict__ woT,
                                                  float* __restrict__ out) {
  __shared__ alignas(16) short sm[32768];
  int lin = blockIdx.x;                       // 512 blocks
  int swz = (lin & 7) * 64 + (lin >> 3);      // XCD gets y in [xcd*2, xcd*2+2)
  int x = swz & 15, y = swz >> 4;
  gemm_core<1>(obuf, woT, out, 2048, 2048, y * 128, x * 128, sm);
}

// ------------------------------------------------------------ attention ----
// R10/R11-VERIFIED kernel, byte-identical (97.5us, VGPR 108).  Swapped-operand
// 32x32: S^T = K @ Q^T ; O^T = V^T @ P^T ; lane owns one q-row's softmax
// state.  XCD-locality 1D grid (bid%8 = bh%8), log2-domain softmax,
// defer-max THR=8, cvt_pk packing, split QK accumulator chains.
// pf slot assignment FROZEN from R4.  (R12's cl2-fold + PV-split reverted:
// VGPR 108->128 regressed MfmaUtil 30.7->28.2.)
__global__ __launch_bounds__(256, 2) void attn_kernel(
    const short* __restrict__ qb, const short* __restrict__ kb,
    const short* __restrict__ vt, short* __restrict__ ob,
    const float* __restrict__ cosT, const float* __restrict__ sinT) {
  // shorts: K bufs @0,8192 ([64 keys][128 d]); V bufs @16384,24576 ([128 d][64 keys])
  __shared__ alignas(16) short sm[32768];
  const int lane = threadIdx.x & 63, w = threadIdx.x >> 6;
  const int ql = lane & 31, hi = lane >> 5;
  const int qt = blockIdx.x >> 5, bh = blockIdx.x & 31;   // bid = qt*32+bh -> XCD=bh%8
  const int b = bh >> 4, h = bh & 15;
  const int q0w = qt * 128 + w * 32;
  const int qrow = q0w + ql;

  // ---- Q load (B-fragment layout: lane q=ql, d = db*16 + hi*8 + j) + RoPE
  bf16x8 qf[8];
  {
    const short* qp = qb + ((size_t)(b * 2048 + qrow)) * 2048 + h * 128;
#pragma unroll
    for (int db = 0; db < 8; ++db) qf[db] = *(const bf16x8*)(qp + db * 16 + hi * 8);
    const float* cp = cosT + qrow * 32;
    const float* sp = sinT + qrow * 32;
#pragma unroll
    for (int db = 0; db < 2; ++db)
#pragma unroll
      for (int j = 0; j < 8; ++j) {
        int i = db * 16 + hi * 8 + j;
        float x1 = b2f(qf[db][j]), x2 = b2f(qf[db + 2][j]);
        float cv = cp[i], sv = sp[i];
        qf[db][j]     = f2bf(x1 * cv - x2 * sv);
        qf[db + 2][j] = f2bf(x1 * sv + x2 * cv);
      }
  }

  f32x16 o[4];
#pragma unroll
  for (int m4 = 0; m4 < 4; ++m4)
#pragma unroll
    for (int r = 0; r < 16; ++r) o[m4][r] = 0.f;
  float mrun = -3.0e38f, lrun = 0.f;

  auto STAGE = [&](int buf, int kt) {
    // K tile [64 keys][128 d]: linear LDS dest, inverse-swizzled global src.
#pragma unroll
    for (int i = 0; i < 4; ++i) {
      int r = w * 16 + i * 4 + (lane >> 4);
      int cch = lane & 15;
      const short* gp = kb + ((size_t)(b * 2048 + kt * 64 + r)) * 2048 + h * 128 +
                        ((cch ^ (r & 7)) << 3);
      GLDS(gp, sm + buf * 8192 + w * 2048 + i * 512);
    }
    // V^T tile [128 d][64 keys]
#pragma unroll
    for (int i = 0; i < 4; ++i) {
      int rd = w * 32 + i * 8 + (lane >> 3);
      int cch = lane & 7;
      const short* gp = vt + ((size_t)(b * 2048 + h * 128 + rd)) * 2048 + kt * 64 +
                        ((cch ^ (rd & 7)) << 3);
      GLDS(gp, sm + 16384 + buf * 8192 + w * 2048 + i * 512);
    }
  };

  const float cl2 = 0.12752744590518352f;   // (1/sqrt(128)) * log2(e)
  STAGE(0, 0);
  __syncthreads();
  int buf = 0;
  for (int kt = 0; kt < 32; ++kt) {
    if (kt + 1 < 32) STAGE(buf ^ 1, kt + 1);
    const short* Ks = sm + buf * 8192;
    const short* Vs = sm + 16384 + buf * 8192;

    // ---- QK^T (swapped): skt[kb2] = S^T[key block kb2][q]; two independent
    // 4-long MFMA chains per kb2 (half the dep chain), cl2 folded in combine.
    f32x16 skt[2];
    __builtin_amdgcn_s_setprio(1);
#pragma unroll
    for (int kb2 = 0; kb2 < 2; ++kb2) {
      f32x16 a0, a1;
#pragma unroll
      for (int r = 0; r < 16; ++r) { a0[r] = 0.f; a1[r] = 0.f; }
      int krow = kb2 * 32 + ql;
#pragma unroll
      for (int db = 0; db < 4; ++db) {
        bf16x8 kf = *(const bf16x8*)(Ks + krow * 128 + (((db * 2 + hi) ^ (krow & 7)) << 3));
        a0 = __builtin_amdgcn_mfma_f32_32x32x16_bf16(kf, qf[db], a0, 0, 0, 0);
      }
#pragma unroll
      for (int db = 4; db < 8; ++db) {
        bf16x8 kf = *(const bf16x8*)(Ks + krow * 128 + (((db * 2 + hi) ^ (krow & 7)) << 3));
        a1 = __builtin_amdgcn_mfma_f32_32x32x16_bf16(kf, qf[db], a1, 0, 0, 0);
      }
#pragma unroll
      for (int r = 0; r < 16; ++r) skt[kb2][r] = (a0[r] + a1[r]) * cl2;
    }
    __builtin_amdgcn_s_setprio(0);

    // ---- row-max via max tree (4 chains of 8, then combine, then half-swap)
    float t0, t1, t2, t3;
    t0 = fmaxf(fmaxf(fmaxf(fmaxf(skt[0][0], skt[0][4]), skt[0][8]),
                     fmaxf(skt[0][12], skt[1][0])),
               fmaxf(fmaxf(skt[1][4], skt[1][8]), skt[1][12]));
    t1 = fmaxf(fmaxf(fmaxf(fmaxf(skt[0][1], skt[0][5]), skt[0][9]),
                     fmaxf(skt[0][13], skt[1][1])),
               fmaxf(fmaxf(skt[1][5], skt[1][9]), skt[1][13]));
    t2 = fmaxf(fmaxf(fmaxf(fmaxf(skt[0][2], skt[0][6]), skt[0][10]),
                     fmaxf(skt[0][14], skt[1][2])),
               fmaxf(fmaxf(skt[1][6], skt[1][10]), skt[1][14]));
    t3 = fmaxf(fmaxf(fmaxf(fmaxf(skt[0][3], skt[0][7]), skt[0][11]),
                     fmaxf(skt[0][15], skt[1][3])),
               fmaxf(fmaxf(skt[1][7], skt[1][11]), skt[1][15]));
    float tmax = fmaxf(fmaxf(t0, t1), fmaxf(t2, t3));
    tmax = fmaxf(tmax, __shfl_xor(tmax, 32));

    // ---- defer-max (T13): rescale only when max grew by > 8 (log2 domain)
    if (!__all(tmax <= mrun + 8.0f)) {
      float mn = fmaxf(mrun, tmax);
      float fr = __builtin_amdgcn_exp2f(mrun - mn);
      mrun = mn;
      lrun *= fr;
#pragma unroll
      for (int m4 = 0; m4 < 4; ++m4)
#pragma unroll
        for (int r = 0; r < 16; ++r) o[m4][r] *= fr;
    }
    // ---- exp2 in place + row-sum
    float s0 = 0.f, s1 = 0.f, s2 = 0.f, s3 = 0.f;
#pragma unroll
    for (int kb2 = 0; kb2 < 2; ++kb2)
#pragma unroll
      for (int r = 0; r < 16; r += 4) {
        skt[kb2][r]     = __builtin_amdgcn_exp2f(skt[kb2][r] - mrun);
        skt[kb2][r + 1] = __builtin_amdgcn_exp2f(skt[kb2][r + 1] - mrun);
        skt[kb2][r + 2] = __builtin_amdgcn_exp2f(skt[kb2][r + 2] - mrun);
        skt[kb2][r + 3] = __builtin_amdgcn_exp2f(skt[kb2][r + 3] - mrun);
        s0 += skt[kb2][r];     s1 += skt[kb2][r + 1];
        s2 += skt[kb2][r + 2]; s3 += skt[kb2][r + 3];
      }
    float psum = (s0 + s1) + (s2 + s3);
    psum += __shfl_xor(psum, 32);
    lrun += psum;

    // ---- P -> bf16 P^T B-fragments (slot assignment FROZEN from R4).
    bf16x8 pf[4];
#pragma unroll
    for (int kb2 = 0; kb2 < 2; ++kb2) {
#pragma unroll
      for (int half = 0; half < 2; ++half) {
        unsigned a0 = cvtpk(skt[kb2][half * 8 + 0], skt[kb2][half * 8 + 1]);
        unsigned a1 = cvtpk(skt[kb2][half * 8 + 2], skt[kb2][half * 8 + 3]);
        unsigned b0 = cvtpk(skt[kb2][half * 8 + 4], skt[kb2][half * 8 + 5]);
        unsigned b1 = cvtpk(skt[kb2][half * 8 + 6], skt[kb2][half * 8 + 7]);
        unsigned pa0 = __shfl_xor(a0, 32), pa1 = __shfl_xor(a1, 32);
        unsigned pb0 = __shfl_xor(b0, 32), pb1 = __shfl_xor(b1, 32);
        union { unsigned u[4]; bf16x8 v; } tmp;
        tmp.u[0] = hi ? pb0 : a0;
        tmp.u[1] = hi ? pb1 : a1;
        tmp.u[2] = hi ? b0 : pa0;
        tmp.u[3] = hi ? b1 : pa1;
        pf[kb2 * 2 + half] = tmp.v;
      }
    }

    // ---- PV (swapped): O^T[d][q] += V^T @ P^T
    __builtin_amdgcn_s_setprio(1);
#pragma unroll
    for (int m4 = 0; m4 < 4; ++m4) {
      int rd = m4 * 32 + ql;
#pragma unroll
      for (int ks = 0; ks < 4; ++ks) {
        bf16x8 vf = *(const bf16x8*)(Vs + rd * 64 + (((ks * 2 + hi) ^ (rd & 7)) << 3));
        o[m4] = __builtin_amdgcn_mfma_f32_32x32x16_bf16(vf, pf[ks], o[m4], 0, 0, 0);
      }
    }
    __builtin_amdgcn_s_setprio(0);
    __syncthreads();
    buf ^= 1;
  }

  // ---- epilogue: O^T -> LDS transpose (padded rows) -> coalesced bf16 store
  float il = 1.0f / lrun;
  short* E = sm + w * 4352;                    // [32 q][136 shorts], 16B-aligned rows
#pragma unroll
  for (int m4 = 0; m4 < 4; ++m4)
#pragma unroll
    for (int r = 0; r < 16; r += 2) {
      int d = m4 * 32 + (r & 3) + 8 * (r >> 2) + 4 * hi;
      unsigned pk = cvtpk(o[m4][r] * il, o[m4][r + 1] * il);
      *(unsigned*)(E + ql * 136 + d) = pk;
    }
  asm volatile("s_waitcnt lgkmcnt(0)" ::: "memory");   // wave-private region
#pragma unroll
  for (int it = 0; it < 8; ++it) {
    int row = it * 4 + (lane >> 4);
    int ch = lane & 15;
    bf16x8 v = *(const bf16x8*)(E + row * 136 + ch * 8);
    *(bf16x8*)(ob + ((size_t)(b * 2048 + q0w + row)) * 2048 + h * 128 + ch * 8) = v;
  }
}

// --------------------------------------------------------------- launch ----
extern "C" void kernel_launch(void* const* d_in, const int* in_sizes, int n_in,
                              void* d_out, int out_size, void* d_ws, size_t ws_size,
                              hipStream_t stream) {
  (void)in_sizes; (void)n_in; (void)out_size; (void)ws_size;
  const float* x  = (const float*)d_in[0];
  const int*   pos = (const int*)d_in[1];
  const float* Wq = (const float*)d_in[2];
  const float* Wc = (const float*)d_in[3];
  const float* Wk = (const float*)d_in[4];
  const float* Wv = (const float*)d_in[5];
  const float* Wo = (const float*)d_in[6];

  char* ws = (char*)d_ws;
  short* xb   = (short*)(ws);                 // x bf16            16.78 MB
  short* qb   = (short*)(ws + 16777216);      // q (pre-rope)      16.78 MB
  short* kvb  = (short*)(ws + 33554432);      // latent            4.19 MB
  short* kb   = (short*)(ws + 37748736);      // k                 16.78 MB
  short* vtb  = (short*)(ws + 54525952);      // v transposed      16.78 MB
  short* obuf = (short*)(ws + 71303168);      // attn out          16.78 MB
  short* wqT  = (short*)(ws + 88080384);      // Wq^T              8.39 MB
  short* wcT  = (short*)(ws + 96468992);      // Wc^T              2.10 MB
  short* wkT  = (short*)(ws + 98566144);      // Wk^T              2.10 MB
  short* wvT  = (short*)(ws + 100663296);     // Wv^T              2.10 MB
  short* woT  = (short*)(ws + 102760448);     // Wo^T              8.39 MB
  float* cosT = (float*)(ws + 111149056);     // 0.26 MB
  float* sinT = (float*)(ws + 111411200);     // 0.26 MB

  prep_kernel<<<19712, 256, 0, stream>>>(x, xb, Wq, wqT, Wo, woT, Wc, wcT,
                                         Wk, wkT, Wv, wvT, pos, cosT, sinT);

  gemm_qc<<<640, 256, 0, stream>>>(xb, wqT, wcT, qb, kvb);
  gemm_kv<<<1024, 256, 0, stream>>>(kvb, wkT, wvT, kb, vtb);

  attn_kernel<<<512, 256, 0, stream>>>(qb, kb, vtb, obuf, cosT, sinT);

  gemm_wo<<<512, 256, 0, stream>>>(obuf, woT, (float*)d_out);
}